// Round 7
// baseline (421.163 us; speedup 1.0000x reference)
//
// R7: persistent bf16 A-slab in LDS (16 BK-sections, 133 KB) — context pass
// reads LDS instead of re-reading 256 MiB of enc through a thrashing L3.
// K-loop structure/barriers unchanged from R6; 1 block/CU (LDS-limited).
#include <hip/hip_runtime.h>
#include <hip/hip_bf16.h>
#include <math.h>

#define B_  32
#define T_  4096
#define H_  256
#define D_  512

// ws layout (bytes):
//   pre   : float [32*256]        @ 0       (h_proj + b_attn)
//   we_hi : ushort[256*512]       @ 32768   (bf16 W_e, per-BK-tile + XOR-swizzled)
//   p     : float [32*4096]       @ 294912  (exp(s - m_blk) per row)
//   ml    : float2[1024]          @ 819200  (per-tile m_blk, l_blk)
//   pctx  : float [1024*512]      @ 827392  (per-tile partial context)
#define WS_PRE    0
#define WS_WEHI   32768
#define WS_P      294912
#define WS_ML     819200
#define WS_PCTX   827392

using short8  = __attribute__((ext_vector_type(8))) short;
using float4v = __attribute__((ext_vector_type(4))) float;

// RNE f32->bf16 pair pack (v_cvt_pk_bf16_f32)
__device__ __forceinline__ unsigned cvt2_bf16(float lo, float hi) {
    union { __hip_bfloat162 h; unsigned u; } cv;
    cv.h = __float22bfloat162_rn(make_float2(lo, hi));
    return cv.u;
}
__device__ __forceinline__ short8 cvt8_bf16(const float* a) {
    union { unsigned u[4]; short8 s; } r;
    r.u[0] = cvt2_bf16(a[0], a[1]);
    r.u[1] = cvt2_bf16(a[2], a[3]);
    r.u[2] = cvt2_bf16(a[4], a[5]);
    r.u[3] = cvt2_bf16(a[6], a[7]);
    return r.s;
}

// bf16 (as ushort) -> f32 exact
__device__ __forceinline__ float bf16_to_f32(unsigned short u) {
    unsigned v = ((unsigned)u) << 16;
    return __uint_as_float(v);
}

// tanh(x) = 1 - 2/(e^{2x}+1); |err| ~1e-7, far below the bf16 score floor.
__device__ __forceinline__ float fast_tanh(float x) {
    float e = __expf(2.0f * x);
    return 1.0f - 2.0f * __builtin_amdgcn_rcpf(e + 1.0f);
}

// ---------------------------------------------------------------- prep ------
// blocks 0..31 : h_proj + b_attn
// blocks 32..63: W_e -> bf16, TILED per BK=32 (16KB tiles), XOR-swizzled:
//   (n,k): t=k>>5, quad=(k&31)>>3, e=k&7, slot=quad^((n>>1)&3);
//   dst = t*8192 + n*32 + slot*8 + e. gemm reads fragments directly from
//   this layout (per-wave 1KB contiguous chunks — fully coalesced).
__global__ __launch_bounds__(256)
void prep_kernel(const float* __restrict__ hidden,
                 const float* __restrict__ W_attn,
                 const float* __restrict__ b_attn,
                 unsigned char* __restrict__ ws) {
    int blk = blockIdx.x;
    int tid = threadIdx.x;
    if (blk < 32) {
        int b = blk, h = tid;
        const float4* hv = (const float4*)(hidden + b * D_);
        const float4* wv = (const float4*)(W_attn + (size_t)h * 1024);
        float s = 0.f;
        #pragma unroll 4
        for (int d4 = 0; d4 < D_ / 4; ++d4) {
            float4 a = hv[d4], w = wv[d4];
            s += a.x * w.x + a.y * w.y + a.z * w.z + a.w * w.w;
        }
        ((float*)(ws + WS_PRE))[b * H_ + h] = s + b_attn[h];
    } else {
        int q = (blk - 32) * 256 + tid;            // 0..8191
        unsigned short* whi = (unsigned short*)(ws + WS_WEHI);
        #pragma unroll
        for (int i = 0; i < 4; ++i) {
            int idx4 = q + i * 8192;               // float4 index over [256][128]
            int n = idx4 >> 7, k = (idx4 & 127) << 2;
            int t = k >> 5, kin = k & 31;
            int quad = kin >> 3, e = kin & 7;      // e in {0,4}
            int slot = quad ^ ((n >> 1) & 3);
            float4 w = *(const float4*)(W_attn + (size_t)n * 1024 + 512 + k);
            unsigned lo = cvt2_bf16(w.x, w.y);
            unsigned hi = cvt2_bf16(w.z, w.w);
            unsigned short* dst = whi + t * 8192 + n * 32 + slot * 8 + e;
            *(uint2*)dst = make_uint2(lo, hi);     // 8B aligned (e in {0,4})
        }
    }
}

// ------------------------------- GEMM + tanh + v-dot + local softmax + pctx -
// grid = 1024 blocks (M-tiles of 128), 512 threads (8 waves, 2m x 4n, 64x64).
// BM=128 x BN=256 (full N) x K=512, BK=32.
// A: HBM -> regs (2 sets, 2 slabs ahead) -> bf16 -> PERSISTENT LDS slab
//    [128][520] (16 disjoint BK-sections; write section kk+1 while reading
//    kk — same one-lgkm-barrier-per-iter as the old double buffer).
// B: L2-resident ws tiles -> registers, 1 iter ahead (no LDS).
// Context pass reads the bf16 slab from LDS — enc crosses HBM ONCE.
#define BM 128
#define BN 256
#define BK 32
#define LDT 520  // slab row stride in ushorts: 1040 B = 65*16 (b128-aligned)
#define KIT 16

__global__ __launch_bounds__(512, 2)
void gemm_scores_kernel(const float* __restrict__ enc,
                        unsigned char* __restrict__ ws,
                        const float* __restrict__ v) {
    __shared__ unsigned short sE[BM * LDT];        // 133,120 B persistent slab
    __shared__ float sScoreP[4][BM];               // per-wn partial scores
    __shared__ float sP[BM];
    __shared__ float sRed[4];

    const float*          pre = (const float*)(ws + WS_PRE);
    const unsigned short* weh = (const unsigned short*)(ws + WS_WEHI);

    int tid = threadIdx.x;
    int m0  = blockIdx.x * BM;
    int b   = m0 >> 12;

    // A staging: rowA consecutive within a wave -> contiguous LDS writes
    int rowA = tid & 127, cgA = tid >> 7;          // 4 col-groups of 8 floats
    const float* gA = enc + (size_t)(m0 + rowA) * D_ + cgA * 8;

    int wave = tid >> 6, lane = tid & 63;
    int wm = wave & 1, wn = wave >> 1;             // 2 x 4 waves, 64x64 tiles
    int quad = lane >> 4, l16 = lane & 15;

    // B fragment base: c = wn*64 + j*16 + l16; addr = c*32 + slot*8 ushorts
    // with slot = quad ^ ((c>>1)&3) = quad ^ ((l16>>1)&3)  (j,wn-independent)
    int slotB = quad ^ ((l16 >> 1) & 3);
    const unsigned short* bBase = weh + (wn * 64 + l16) * 32 + slotB * 8;

    float4v acc[4][4] = {};

    float aX[8], aY[8];                            // two A prefetch sets
    short8 bhA[4], bhB[4];                         // two B fragment sets

    // ---- preamble: slab0 -> LDS section 0, tile0 -> bhA; issue slab1/tile1
    {
        const float4* p0 = (const float4*)gA;
        float4 x0 = p0[0], x1 = p0[1];
        #pragma unroll
        for (int j = 0; j < 4; ++j)
            bhA[j] = *(const short8*)(bBase + j * 512);
        const float4* p1 = (const float4*)(gA + BK);
        float4 y0 = p1[0], y1 = p1[1];
        #pragma unroll
        for (int j = 0; j < 4; ++j)
            bhB[j] = *(const short8*)(bBase + 8192 + j * 512);

        float tmp[8];
        *(float4*)tmp = x0; *(float4*)(tmp + 4) = x1;
        *(short8*)&sE[rowA * LDT + cgA * 8] = cvt8_bf16(tmp);
        *(float4*)aY = y0; *(float4*)(aY + 4) = y1;
    }
    __builtin_amdgcn_s_waitcnt(0xc07f);   // lgkmcnt(0) only
    __builtin_amdgcn_s_barrier();

    // One k-step. Bcur holds tile kk (loaded last iter); Bnxt <- tile kk+1.
    // Acons holds slab kk+1 (written to section kk+1 this iter); Aload <- kk+2.
#define K_STEP(kk, Acons, Aload, Bcur, Bnxt)                                  \
    {                                                                         \
        if ((kk) + 1 < KIT) {                                                 \
            const unsigned short* pb = bBase + ((kk) + 1) * 8192;             \
            Bnxt[0] = *(const short8*)(pb);                                   \
            Bnxt[1] = *(const short8*)(pb + 512);                             \
            Bnxt[2] = *(const short8*)(pb + 1024);                            \
            Bnxt[3] = *(const short8*)(pb + 1536);                            \
        }                                                                     \
        if ((kk) + 2 < KIT) {                                                 \
            const float4* pa = (const float4*)(gA + ((kk) + 2) * BK);         \
            *(float4*)(Aload) = pa[0]; *(float4*)((Aload) + 4) = pa[1];       \
        }                                                                     \
        short8 ah[4];                                                         \
        _Pragma("unroll")                                                     \
        for (int i = 0; i < 4; ++i) {                                         \
            int r = wm * 64 + i * 16 + l16;                                   \
            ah[i] = *(const short8*)&sE[r * LDT + (kk) * BK + quad * 8];      \
        }                                                                     \
        _Pragma("unroll")                                                     \
        for (int i = 0; i < 4; ++i)                                           \
            _Pragma("unroll")                                                 \
            for (int j = 0; j < 4; ++j)                                       \
                acc[i][j] = __builtin_amdgcn_mfma_f32_16x16x32_bf16(          \
                    ah[i], Bcur[j], acc[i][j], 0, 0, 0);                      \
        if ((kk) + 1 < KIT) {                                                 \
            *(short8*)&sE[rowA * LDT + ((kk) + 1) * BK + cgA * 8] =           \
                cvt8_bf16(Acons);                                             \
            __builtin_amdgcn_s_waitcnt(0xc07f);                               \
            __builtin_amdgcn_s_barrier();                                     \
        }                                                                     \
    }

    for (int kt = 0; kt < 8; ++kt) {
        K_STEP(2 * kt,     aY, aX, bhA, bhB)
        K_STEP(2 * kt + 1, aX, aY, bhB, bhA)
    }
#undef K_STEP

    // ---- scores: energy = tanh(acc + pre[b][n]); rowsum += energy * v[n]
    float rowsum[4][4] = {};
    #pragma unroll
    for (int j = 0; j < 4; ++j) {
        int n = wn * 64 + j * 16 + l16;
        float pv = pre[b * H_ + n];
        float vv = v[n];
        #pragma unroll
        for (int i = 0; i < 4; ++i)
            #pragma unroll
            for (int r = 0; r < 4; ++r)
                rowsum[i][r] += fast_tanh(acc[i][j][r] + pv) * vv;
    }
    #pragma unroll
    for (int i = 0; i < 4; ++i)
        #pragma unroll
        for (int r = 0; r < 4; ++r) {
            float s = rowsum[i][r];
            s += __shfl_xor(s, 1);
            s += __shfl_xor(s, 2);
            s += __shfl_xor(s, 4);
            s += __shfl_xor(s, 8);
            rowsum[i][r] = s;
        }
    if (l16 == 0) {
        #pragma unroll
        for (int i = 0; i < 4; ++i)
            #pragma unroll
            for (int r = 0; r < 4; ++r) {
                int row = wm * 64 + i * 16 + quad * 4 + r;
                sScoreP[wn][row] = rowsum[i][r];   // no atomics: unique writer
            }
    }
    __syncthreads();

    // ---- local softmax over the 128 rows
    float sval = 0.f;
    if (tid < 128) {
        sval = sScoreP[0][tid] + sScoreP[1][tid]
             + sScoreP[2][tid] + sScoreP[3][tid];
        float m = sval;
        #pragma unroll
        for (int off = 32; off; off >>= 1) m = fmaxf(m, __shfl_xor(m, off));
        if (lane == 0) sRed[wave] = m;
    }
    __syncthreads();
    float m_blk = fmaxf(sRed[0], sRed[1]);
    if (tid < 128) {
        float p = expf(sval - m_blk);
        sP[tid] = p;
        ((float*)(ws + WS_P))[m0 + tid] = p;
        float l = p;
        #pragma unroll
        for (int off = 32; off; off >>= 1) l += __shfl_xor(l, off);
        if (lane == 0) sRed[2 + wave] = l;
    }
    __syncthreads();
    if (tid == 0) {
        float2 ml = make_float2(m_blk, sRed[2] + sRed[3]);
        ((float2*)(ws + WS_ML))[blockIdx.x] = ml;
    }

    // ---- partial context from the LDS bf16 slab (no global re-read)
    int colg = tid & 127, rgrp = tid >> 7;     // 128 d-groups x 4 rows in flight
    float4 c4 = {0.f, 0.f, 0.f, 0.f};
    #pragma unroll 4
    for (int s = 0; s < 32; ++s) {
        int r = rgrp + 4 * s;
        float w = sP[r];
        uint2 raw = *(const uint2*)&sE[r * LDT + colg * 4];   // 4 bf16, 8B aligned
        c4.x += w * bf16_to_f32((unsigned short)(raw.x & 0xffffu));
        c4.y += w * bf16_to_f32((unsigned short)(raw.x >> 16));
        c4.z += w * bf16_to_f32((unsigned short)(raw.y & 0xffffu));
        c4.w += w * bf16_to_f32((unsigned short)(raw.y >> 16));
    }
    __syncthreads();                            // all slab reads done
    float4* red4 = (float4*)sE;                 // overlay reduction buffer
    red4[tid] = c4;
    __syncthreads();
    if (rgrp == 0) {
        float4 a0 = red4[colg], a1 = red4[colg + 128];
        float4 a2 = red4[colg + 256], a3 = red4[colg + 384];
        float4 o;
        o.x = a0.x + a1.x + a2.x + a3.x;
        o.y = a0.y + a1.y + a2.y + a3.y;
        o.z = a0.z + a1.z + a2.z + a3.z;
        o.w = a0.w + a1.w + a2.w + a3.w;
        ((float4*)(ws + WS_PCTX))[blockIdx.x * 128 + colg] = o;
    }
}

// ------------------------------------------------------------ finalize ------
// one block per batch: combine 32 tile partials, write weights + context.
__global__ __launch_bounds__(512)
void finalize_kernel(const unsigned char* __restrict__ ws,
                     float* __restrict__ out_ctx,
                     float* __restrict__ out_w) {
    __shared__ float sm[32], sl[32], sscale[32];
    int b = blockIdx.x, tid = threadIdx.x;
    const float2* ml  = ((const float2*)(ws + WS_ML)) + b * 32;
    if (tid < 32) {
        float2 v = ml[tid];
        sm[tid] = v.x; sl[tid] = v.y;
    }
    __syncthreads();
    float m = -1e30f;
    #pragma unroll
    for (int i = 0; i < 32; ++i) m = fmaxf(m, sm[i]);
    float l = 0.f;
    #pragma unroll
    for (int i = 0; i < 32; ++i) l += sl[i] * expf(sm[i] - m);
    float inv = 1.0f / l;
    if (tid < 32) sscale[tid] = expf(sm[tid] - m) * inv;
    __syncthreads();

    // weights: 4096 per batch, 8 per thread (same tile per group of 8)
    {
        const float4* pb = (const float4*)((const float*)(ws + WS_P) + (size_t)b * T_);
        float4* wb = (float4*)(out_w + (size_t)b * T_);
        int t0 = tid * 2;                 // float4 index; tile = (tid*8)>>7
        float sc = sscale[tid >> 4];
        float4 x = pb[t0], y = pb[t0 + 1];
        x.x *= sc; x.y *= sc; x.z *= sc; x.w *= sc;
        y.x *= sc; y.y *= sc; y.z *= sc; y.w *= sc;
        wb[t0] = x; wb[t0 + 1] = y;
    }
    // context: 512 d per batch, 1 per thread
    {
        const float* pc = (const float*)(ws + WS_PCTX) + (size_t)b * 32 * D_;
        float c = 0.f;
        #pragma unroll
        for (int i = 0; i < 32; ++i) c += pc[i * D_ + tid] * sscale[i];
        out_ctx[b * D_ + tid] = c;
    }
}

// ------------------------------------------------------------- launcher -----
extern "C" void kernel_launch(void* const* d_in, const int* in_sizes, int n_in,
                              void* d_out, int out_size, void* d_ws, size_t ws_size,
                              hipStream_t stream) {
    const float* hidden = (const float*)d_in[0];   // (32, 512)
    const float* enc    = (const float*)d_in[1];   // (32, 4096, 512)
    const float* W_attn = (const float*)d_in[2];   // (256, 1024)
    const float* b_attn = (const float*)d_in[3];   // (256,)
    const float* v      = (const float*)d_in[4];   // (256,)
    float* out = (float*)d_out;                    // context(16384) ++ weights(131072)
    unsigned char* ws = (unsigned char*)d_ws;

    prep_kernel<<<64, 256, 0, stream>>>(hidden, W_attn, b_attn, ws);
    gemm_scores_kernel<<<T_ * B_ / BM, 512, 0, stream>>>(enc, ws, v);
    finalize_kernel<<<B_, 512, 0, stream>>>(ws, out, out + B_ * D_);
}

// Round 8
// 393.484 us; speedup vs baseline: 1.0703x; 1.0703x over previous
//
// R8: discriminating quadrant — BM=64 persistent bf16 slab (66.5 KB LDS)
// => 2 blocks/CU AND single enc HBM pass (context from LDS).
// K-loop/B-register path/barrier discipline identical to R6/R7.
#include <hip/hip_runtime.h>
#include <hip/hip_bf16.h>
#include <math.h>

#define B_  32
#define T_  4096
#define H_  256
#define D_  512

// ws layout (bytes):
//   pre   : float [32*256]        @ 0       (h_proj + b_attn)
//   we_hi : ushort[256*512]       @ 32768   (bf16 W_e, per-BK-tile + XOR-swizzled)
//   p     : float [32*4096]       @ 294912  (exp(s - m_blk) per row)
//   ml    : float2[2048]          @ 819200  (per-tile m_blk, l_blk)
//   pctx  : float [2048*512]      @ 835584  (per-tile partial context)
#define WS_PRE    0
#define WS_WEHI   32768
#define WS_P      294912
#define WS_ML     819200
#define WS_PCTX   835584

using short8  = __attribute__((ext_vector_type(8))) short;
using float4v = __attribute__((ext_vector_type(4))) float;

// RNE f32->bf16 pair pack (v_cvt_pk_bf16_f32)
__device__ __forceinline__ unsigned cvt2_bf16(float lo, float hi) {
    union { __hip_bfloat162 h; unsigned u; } cv;
    cv.h = __float22bfloat162_rn(make_float2(lo, hi));
    return cv.u;
}
__device__ __forceinline__ uint2 cvt4_bf16(const float* a) {
    return make_uint2(cvt2_bf16(a[0], a[1]), cvt2_bf16(a[2], a[3]));
}

// bf16 (as ushort) -> f32 exact
__device__ __forceinline__ float bf16_to_f32(unsigned short u) {
    return __uint_as_float(((unsigned)u) << 16);
}

// tanh(x) = 1 - 2/(e^{2x}+1); |err| ~1e-7, far below the bf16 score floor.
__device__ __forceinline__ float fast_tanh(float x) {
    float e = __expf(2.0f * x);
    return 1.0f - 2.0f * __builtin_amdgcn_rcpf(e + 1.0f);
}

// ---------------------------------------------------------------- prep ------
// blocks 0..31 : h_proj + b_attn
// blocks 32..63: W_e -> bf16, TILED per BK=32 (16KB tiles), XOR-swizzled:
//   (n,k): t=k>>5, quad=(k&31)>>3, e=k&7, slot=quad^((n>>1)&3);
//   dst = t*8192 + n*32 + slot*8 + e. gemm reads fragments directly from
//   this layout (per-wave 1KB contiguous chunks — fully coalesced).
__global__ __launch_bounds__(256)
void prep_kernel(const float* __restrict__ hidden,
                 const float* __restrict__ W_attn,
                 const float* __restrict__ b_attn,
                 unsigned char* __restrict__ ws) {
    int blk = blockIdx.x;
    int tid = threadIdx.x;
    if (blk < 32) {
        int b = blk, h = tid;
        const float4* hv = (const float4*)(hidden + b * D_);
        const float4* wv = (const float4*)(W_attn + (size_t)h * 1024);
        float s = 0.f;
        #pragma unroll 4
        for (int d4 = 0; d4 < D_ / 4; ++d4) {
            float4 a = hv[d4], w = wv[d4];
            s += a.x * w.x + a.y * w.y + a.z * w.z + a.w * w.w;
        }
        ((float*)(ws + WS_PRE))[b * H_ + h] = s + b_attn[h];
    } else {
        int q = (blk - 32) * 256 + tid;            // 0..8191
        unsigned short* whi = (unsigned short*)(ws + WS_WEHI);
        #pragma unroll
        for (int i = 0; i < 4; ++i) {
            int idx4 = q + i * 8192;               // float4 index over [256][128]
            int n = idx4 >> 7, k = (idx4 & 127) << 2;
            int t = k >> 5, kin = k & 31;
            int quad = kin >> 3, e = kin & 7;      // e in {0,4}
            int slot = quad ^ ((n >> 1) & 3);
            float4 w = *(const float4*)(W_attn + (size_t)n * 1024 + 512 + k);
            unsigned lo = cvt2_bf16(w.x, w.y);
            unsigned hi = cvt2_bf16(w.z, w.w);
            unsigned short* dst = whi + t * 8192 + n * 32 + slot * 8 + e;
            *(uint2*)dst = make_uint2(lo, hi);     // 8B aligned (e in {0,4})
        }
    }
}

// ------------------------------- GEMM + tanh + v-dot + local softmax + pctx -
// grid = 2048 blocks (M-tiles of 64), 512 threads (8 waves, 2m x 4n, 32x64).
// BM=64 x BN=256 (full N) x K=512, BK=32.
// A: HBM -> regs (2 sets, 2 slabs ahead) -> bf16 -> PERSISTENT LDS slab
//    [64][520] (16 disjoint BK-sections; write section kk+1 while reading kk).
// B: L2-resident ws tiles -> registers, 1 iter ahead (no LDS).
// Context pass reads the bf16 slab from LDS — enc crosses HBM ONCE.
// LDS 67.8 KB -> 2 blocks/CU; launch_bounds(512,4) pins VGPR <= 128.
#define BM 64
#define BN 256
#define BK 32
#define LDT 520  // slab row stride in ushorts: 1040 B (b128-aligned rows)
#define KIT 16

__global__ __launch_bounds__(512, 4)
void gemm_scores_kernel(const float* __restrict__ enc,
                        unsigned char* __restrict__ ws,
                        const float* __restrict__ v) {
    __shared__ unsigned short sE[BM * LDT];        // 66,560 B persistent slab
    __shared__ float sScoreP[4][BM];               // per-wn partial scores
    __shared__ float sP[BM];

    const float*          pre = (const float*)(ws + WS_PRE);
    const unsigned short* weh = (const unsigned short*)(ws + WS_WEHI);

    int tid = threadIdx.x;
    int m0  = blockIdx.x * BM;
    int b   = m0 >> 12;

    // A staging: 8 threads/row, one float4 each (64 rows x 32 cols per slab)
    int rowA = tid >> 3, c8 = (tid & 7) * 4;
    const float* gA = enc + (size_t)(m0 + rowA) * D_ + c8;

    int wave = tid >> 6, lane = tid & 63;
    int wm = wave & 1, wn = wave >> 1;             // 2 x 4 waves, 32x64 tiles
    int quad = lane >> 4, l16 = lane & 15;

    // B fragment base: c = wn*64 + j*16 + l16; addr = c*32 + slot*8 ushorts
    // with slot = quad ^ ((c>>1)&3) = quad ^ ((l16>>1)&3)  (j,wn-independent)
    int slotB = quad ^ ((l16 >> 1) & 3);
    const unsigned short* bBase = weh + (wn * 64 + l16) * 32 + slotB * 8;

    float4v acc[2][4] = {};

    float aX[4], aY[4];                            // two A prefetch sets
    short8 bhA[4], bhB[4];                         // two B fragment sets

    // ---- preamble: slab0 -> LDS section 0, tile0 -> bhA; issue slab1/tile1
    {
        float4 x0 = *(const float4*)gA;
        #pragma unroll
        for (int j = 0; j < 4; ++j)
            bhA[j] = *(const short8*)(bBase + j * 512);
        float4 y0 = *(const float4*)(gA + BK);
        #pragma unroll
        for (int j = 0; j < 4; ++j)
            bhB[j] = *(const short8*)(bBase + 8192 + j * 512);

        float tmp[4];
        *(float4*)tmp = x0;
        *(uint2*)&sE[rowA * LDT + c8] = cvt4_bf16(tmp);
        *(float4*)aY = y0;
    }
    __builtin_amdgcn_s_waitcnt(0xc07f);   // lgkmcnt(0) only
    __builtin_amdgcn_s_barrier();

    // One k-step. Bcur holds tile kk (loaded last iter); Bnxt <- tile kk+1.
    // Acons holds slab kk+1 (written to section kk+1 this iter); Aload <- kk+2.
#define K_STEP(kk, Acons, Aload, Bcur, Bnxt)                                  \
    {                                                                         \
        if ((kk) + 1 < KIT) {                                                 \
            const unsigned short* pb = bBase + ((kk) + 1) * 8192;             \
            Bnxt[0] = *(const short8*)(pb);                                   \
            Bnxt[1] = *(const short8*)(pb + 512);                             \
            Bnxt[2] = *(const short8*)(pb + 1024);                            \
            Bnxt[3] = *(const short8*)(pb + 1536);                            \
        }                                                                     \
        if ((kk) + 2 < KIT) {                                                 \
            *(float4*)(Aload) = *(const float4*)(gA + ((kk) + 2) * BK);       \
        }                                                                     \
        short8 ah[2];                                                         \
        _Pragma("unroll")                                                     \
        for (int i = 0; i < 2; ++i) {                                         \
            int r = wm * 32 + i * 16 + l16;                                   \
            ah[i] = *(const short8*)&sE[r * LDT + (kk) * BK + quad * 8];      \
        }                                                                     \
        _Pragma("unroll")                                                     \
        for (int i = 0; i < 2; ++i)                                           \
            _Pragma("unroll")                                                 \
            for (int j = 0; j < 4; ++j)                                       \
                acc[i][j] = __builtin_amdgcn_mfma_f32_16x16x32_bf16(          \
                    ah[i], Bcur[j], acc[i][j], 0, 0, 0);                      \
        if ((kk) + 1 < KIT) {                                                 \
            *(uint2*)&sE[rowA * LDT + ((kk) + 1) * BK + c8] =                 \
                cvt4_bf16(Acons);                                             \
            __builtin_amdgcn_s_waitcnt(0xc07f);                               \
            __builtin_amdgcn_s_barrier();                                     \
        }                                                                     \
    }

    for (int kt = 0; kt < 8; ++kt) {
        K_STEP(2 * kt,     aY, aX, bhA, bhB)
        K_STEP(2 * kt + 1, aX, aY, bhB, bhA)
    }
#undef K_STEP

    // ---- scores: energy = tanh(acc + pre[b][n]); rowsum += energy * v[n]
    float rowsum[2][4] = {};
    #pragma unroll
    for (int j = 0; j < 4; ++j) {
        int n = wn * 64 + j * 16 + l16;
        float pv = pre[b * H_ + n];
        float vv = v[n];
        #pragma unroll
        for (int i = 0; i < 2; ++i)
            #pragma unroll
            for (int r = 0; r < 4; ++r)
                rowsum[i][r] += fast_tanh(acc[i][j][r] + pv) * vv;
    }
    #pragma unroll
    for (int i = 0; i < 2; ++i)
        #pragma unroll
        for (int r = 0; r < 4; ++r) {
            float s = rowsum[i][r];
            s += __shfl_xor(s, 1);
            s += __shfl_xor(s, 2);
            s += __shfl_xor(s, 4);
            s += __shfl_xor(s, 8);
            rowsum[i][r] = s;
        }
    if (l16 == 0) {
        #pragma unroll
        for (int i = 0; i < 2; ++i)
            #pragma unroll
            for (int r = 0; r < 4; ++r) {
                int row = wm * 32 + i * 16 + quad * 4 + r;
                sScoreP[wn][row] = rowsum[i][r];   // unique writer
            }
    }
    __syncthreads();

    // ---- local softmax over the 64 rows (wave 0 only, full-wave butterfly)
    if (tid < 64) {
        float sval = sScoreP[0][tid] + sScoreP[1][tid]
                   + sScoreP[2][tid] + sScoreP[3][tid];
        float m = sval;
        #pragma unroll
        for (int off = 32; off; off >>= 1) m = fmaxf(m, __shfl_xor(m, off));
        float p = expf(sval - m);
        sP[tid] = p;
        ((float*)(ws + WS_P))[m0 + tid] = p;
        float l = p;
        #pragma unroll
        for (int off = 32; off; off >>= 1) l += __shfl_xor(l, off);
        if (tid == 0)
            ((float2*)(ws + WS_ML))[blockIdx.x] = make_float2(m, l);
    }
    __syncthreads();

    // ---- partial context from the LDS bf16 slab (no global re-read)
    int colg = tid & 127, rgrp = tid >> 7;     // 128 d-groups x 4 rows in flight
    float4 c4 = {0.f, 0.f, 0.f, 0.f};
    #pragma unroll 4
    for (int s = 0; s < 16; ++s) {
        int r = rgrp + 4 * s;
        float w = sP[r];
        uint2 raw = *(const uint2*)&sE[r * LDT + colg * 4];   // 4 bf16, 8B
        c4.x += w * bf16_to_f32((unsigned short)(raw.x & 0xffffu));
        c4.y += w * bf16_to_f32((unsigned short)(raw.x >> 16));
        c4.z += w * bf16_to_f32((unsigned short)(raw.y & 0xffffu));
        c4.w += w * bf16_to_f32((unsigned short)(raw.y >> 16));
    }
    __syncthreads();                            // all slab reads done
    float4* red4 = (float4*)sE;                 // overlay reduction buffer
    red4[tid] = c4;
    __syncthreads();
    if (rgrp == 0) {
        float4 a0 = red4[colg], a1 = red4[colg + 128];
        float4 a2 = red4[colg + 256], a3 = red4[colg + 384];
        float4 o;
        o.x = a0.x + a1.x + a2.x + a3.x;
        o.y = a0.y + a1.y + a2.y + a3.y;
        o.z = a0.z + a1.z + a2.z + a3.z;
        o.w = a0.w + a1.w + a2.w + a3.w;
        ((float4*)(ws + WS_PCTX))[blockIdx.x * 128 + colg] = o;
    }
}

// ------------------------------------------------------------ finalize ------
// one block per batch: combine 64 tile partials, write weights + context.
__global__ __launch_bounds__(512)
void finalize_kernel(const unsigned char* __restrict__ ws,
                     float* __restrict__ out_ctx,
                     float* __restrict__ out_w) {
    __shared__ float sm[64], sl[64], sscale[64];
    int b = blockIdx.x, tid = threadIdx.x;
    const float2* ml  = ((const float2*)(ws + WS_ML)) + b * 64;
    if (tid < 64) {
        float2 v = ml[tid];
        sm[tid] = v.x; sl[tid] = v.y;
    }
    __syncthreads();
    float m = -1e30f;
    #pragma unroll
    for (int i = 0; i < 64; ++i) m = fmaxf(m, sm[i]);
    float l = 0.f;
    #pragma unroll
    for (int i = 0; i < 64; ++i) l += sl[i] * expf(sm[i] - m);
    float inv = 1.0f / l;
    if (tid < 64) sscale[tid] = expf(sm[tid] - m) * inv;
    __syncthreads();

    // weights: 4096 per batch, 8 per thread (rows tid*8..+7, tile = tid>>3)
    {
        const float4* pb = (const float4*)((const float*)(ws + WS_P) + (size_t)b * T_);
        float4* wb = (float4*)(out_w + (size_t)b * T_);
        int t0 = tid * 2;
        float sc = sscale[tid >> 3];
        float4 x = pb[t0], y = pb[t0 + 1];
        x.x *= sc; x.y *= sc; x.z *= sc; x.w *= sc;
        y.x *= sc; y.y *= sc; y.z *= sc; y.w *= sc;
        wb[t0] = x; wb[t0 + 1] = y;
    }
    // context: 512 d per batch, 1 per thread
    {
        const float* pc = (const float*)(ws + WS_PCTX) + (size_t)b * 64 * D_;
        float c = 0.f;
        #pragma unroll
        for (int i = 0; i < 64; ++i) c += pc[i * D_ + tid] * sscale[i];
        out_ctx[b * D_ + tid] = c;
    }
}

// ------------------------------------------------------------- launcher -----
extern "C" void kernel_launch(void* const* d_in, const int* in_sizes, int n_in,
                              void* d_out, int out_size, void* d_ws, size_t ws_size,
                              hipStream_t stream) {
    const float* hidden = (const float*)d_in[0];   // (32, 512)
    const float* enc    = (const float*)d_in[1];   // (32, 4096, 512)
    const float* W_attn = (const float*)d_in[2];   // (256, 1024)
    const float* b_attn = (const float*)d_in[3];   // (256,)
    const float* v      = (const float*)d_in[4];   // (256,)
    float* out = (float*)d_out;                    // context(16384) ++ weights(131072)
    unsigned char* ws = (unsigned char*)d_ws;

    prep_kernel<<<64, 256, 0, stream>>>(hidden, W_attn, b_attn, ws);
    gemm_scores_kernel<<<T_ * B_ / BM, 512, 0, stream>>>(enc, ws, v);
    finalize_kernel<<<B_, 512, 0, stream>>>(ws, out, out + B_ * D_);
}